// Round 10
// baseline (275.579 us; speedup 1.0000x reference)
//
#include <hip/hip_runtime.h>
#include <hip/hip_bf16.h>
#include <hip/hip_fp16.h>
#include <stdint.h>

// ---------------------------------------------------------------------------
// CLIPAttentionPooling. R10: AV occupancy attack (R9 post-mortem: AV ~75-85us,
// 512-thr/49KB-LDS = 2 blocks/CU). New AV: 256-thr, grid 1024 (32 bands x
// 8 cols x splitK=4), 33 KB LDS -> 4 blocks/CU; memset + fp32 atomicAdd
// reduction (no add2, no idle combine). quantT/proj/S unchanged (R8-verified).
// Pipeline: memset(out), quantT, gemm_proj_i8, gemm_s_stats, gemm_av.
// ---------------------------------------------------------------------------

using half8   = __attribute__((ext_vector_type(8))) _Float16;
using float4v = __attribute__((ext_vector_type(4))) float;
using int4v   = __attribute__((ext_vector_type(4))) int;

// q/k int16 grid: covers +-6.0, v = QS*(256*hi+lo)
#define QS        (6.0f / 32768.0f)
#define INV_S     (32768.0f / 6.0f)
#define INV_S256  (128.0f / 6.0f)
#define C_HH      (65536.0f * QS * QS)
#define C_X       (256.0f * QS * QS)

// x grid: +-6.0 ; W grid: +-0.25
#define SX        (6.0f / 32768.0f)
#define SW        (0.25f / 32768.0f)
#define P_HH      (65536.0f * SX * SW)
#define P_X       (256.0f * SX * SW)

#define GLOAD_LDS16(gptr, ldsptr)                                              \
  __builtin_amdgcn_global_load_lds(                                            \
      (__attribute__((address_space(1))) void*)(uintptr_t)(gptr),              \
      (__attribute__((address_space(3))) void*)(unsigned)(uintptr_t)(ldsptr),  \
      16, 0, 0)

// ---------------------------------------------------------------------------
// S GEMM + tile softmax stats. Split-i8 16x16x64, 128x128 tile, BK=64.
__global__ __launch_bounds__(256, 2) void gemm_s_stats(
    const int8_t* __restrict__ Ahi, const int8_t* __restrict__ Alo,
    const int8_t* __restrict__ Bhi, const int8_t* __restrict__ Blo,
    _Float16* __restrict__ E, float2* __restrict__ stats)
{
  __shared__ __align__(16) int8_t sAh[128 * 64];
  __shared__ __align__(16) int8_t sAl[128 * 64];
  __shared__ __align__(16) int8_t sBh[128 * 64];
  __shared__ __align__(16) int8_t sBl[128 * 64];

  const int tid  = threadIdx.x;
  const int wave = tid >> 6;
  const int lane = tid & 63;
  const int quad = lane >> 4;
  const int t16  = lane & 15;
  const int wm   = wave & 1;
  const int wn   = wave >> 1;
  const int row0 = blockIdx.y * 128;
  const int col0 = blockIdx.x * 128;

  const int seg  = lane & 3;
  const int rsub = lane >> 2;

  int4v hh[4][4], cc[4][4];
#pragma unroll
  for (int i = 0; i < 4; ++i)
#pragma unroll
    for (int j = 0; j < 4; ++j) {
      hh[i][j] = (int4v){0, 0, 0, 0};
      cc[i][j] = (int4v){0, 0, 0, 0};
    }

  for (int k0 = 0; k0 < 1024; k0 += 64) {
#pragma unroll
    for (int r = 0; r < 2; ++r) {
      const int trow = r * 64 + wave * 16;
      const size_t goffA = (size_t)(row0 + trow + rsub) * 2048 + k0 + seg * 16;
      const size_t goffB = (size_t)(col0 + trow + rsub) * 2048 + k0 + seg * 16;
      GLOAD_LDS16(Ahi + goffA, &sAh[trow * 64]);
      GLOAD_LDS16(Alo + goffA, &sAl[trow * 64]);
      GLOAD_LDS16(Bhi + goffB, &sBh[trow * 64]);
      GLOAD_LDS16(Blo + goffB, &sBl[trow * 64]);
    }
    __syncthreads();

    int4v ah[4], al[4], bh[4], bl[4];
#pragma unroll
    for (int i = 0; i < 4; ++i) {
      const int ar = (wm * 64 + i * 16 + t16) * 64 + quad * 16;
      ah[i] = *(const int4v*)&sAh[ar];
      al[i] = *(const int4v*)&sAl[ar];
    }
#pragma unroll
    for (int j = 0; j < 4; ++j) {
      const int br = (wn * 64 + j * 16 + t16) * 64 + quad * 16;
      bh[j] = *(const int4v*)&sBh[br];
      bl[j] = *(const int4v*)&sBl[br];
    }

#pragma unroll
    for (int i = 0; i < 4; ++i)
#pragma unroll
      for (int j = 0; j < 4; ++j) {
        hh[i][j] = __builtin_amdgcn_mfma_i32_16x16x64_i8(ah[i], bh[j], hh[i][j], 0, 0, 0);
        cc[i][j] = __builtin_amdgcn_mfma_i32_16x16x64_i8(ah[i], bl[j], cc[i][j], 0, 0, 0);
        cc[i][j] = __builtin_amdgcn_mfma_i32_16x16x64_i8(al[i], bh[j], cc[i][j], 0, 0, 0);
      }
    __syncthreads();
  }

  // ---- epilogue: tile-local softmax stats (R8-verified) --------------------
  float* red = (float*)sAh;

  float vv[4][4][4];
  float rmax[4][4];
#pragma unroll
  for (int i = 0; i < 4; ++i)
#pragma unroll
    for (int r = 0; r < 4; ++r) {
      float mx = -3.0e38f;
#pragma unroll
      for (int j = 0; j < 4; ++j) {
        float v = C_HH * (float)hh[i][j][r] + C_X * (float)cc[i][j][r];
        vv[i][j][r] = v;
        mx = fmaxf(mx, v);
      }
      mx = fmaxf(mx, __shfl_xor(mx, 1));
      mx = fmaxf(mx, __shfl_xor(mx, 2));
      mx = fmaxf(mx, __shfl_xor(mx, 4));
      mx = fmaxf(mx, __shfl_xor(mx, 8));
      rmax[i][r] = mx;
    }
  if (t16 == 0) {
#pragma unroll
    for (int i = 0; i < 4; ++i)
#pragma unroll
      for (int r = 0; r < 4; ++r)
        red[wn * 128 + wm * 64 + i * 16 + quad * 4 + r] = rmax[i][r];
  }
  __syncthreads();

  float mrow[4][4];
#pragma unroll
  for (int i = 0; i < 4; ++i)
#pragma unroll
    for (int r = 0; r < 4; ++r) {
      const int row = wm * 64 + i * 16 + quad * 4 + r;
      mrow[i][r] = fmaxf(red[row], red[128 + row]);
    }

  float rsum[4][4];
#pragma unroll
  for (int i = 0; i < 4; ++i)
#pragma unroll
    for (int r = 0; r < 4; ++r) {
      float s = 0.f;
#pragma unroll
      for (int j = 0; j < 4; ++j) {
        float e = __expf(vv[i][j][r] - mrow[i][r]);
        vv[i][j][r] = e;
        s += e;
      }
      s += __shfl_xor(s, 1);
      s += __shfl_xor(s, 2);
      s += __shfl_xor(s, 4);
      s += __shfl_xor(s, 8);
      rsum[i][r] = s;
    }
  if (t16 == 0) {
#pragma unroll
    for (int i = 0; i < 4; ++i)
#pragma unroll
      for (int r = 0; r < 4; ++r)
        red[256 + wn * 128 + wm * 64 + i * 16 + quad * 4 + r] = rsum[i][r];
  }
  __syncthreads();

#pragma unroll
  for (int i = 0; i < 4; ++i) {
#pragma unroll
    for (int j = 0; j < 4; ++j) {
#pragma unroll
      for (int r = 0; r < 4; ++r) {
        const int crow = row0 + wm * 64 + i * 16 + quad * 4 + r;
        const int ccol = col0 + wn * 64 + j * 16 + t16;
        E[(size_t)crow * 4096 + ccol] = (_Float16)vv[i][j][r];
      }
    }
  }
  if (wn == 0 && t16 == 0) {
#pragma unroll
    for (int i = 0; i < 4; ++i)
#pragma unroll
      for (int r = 0; r < 4; ++r) {
        const int row = wm * 64 + i * 16 + quad * 4 + r;
        const float l = red[256 + row] + red[256 + 128 + row];
        stats[(size_t)(row0 + row) * 32 + blockIdx.x] =
            make_float2(mrow[i][r], l);
      }
  }
}

// ---------------------------------------------------------------------------
// proj: qk = x Wqk^T + bias, split-i8 3-MFMA, bias + int16-grid quant epilogue.
__global__ __launch_bounds__(256, 2) void gemm_proj_i8(
    const int8_t* __restrict__ Ahi, const int8_t* __restrict__ Alo,
    const int8_t* __restrict__ Bhi, const int8_t* __restrict__ Blo,
    const float* __restrict__ biasQ, const float* __restrict__ biasK,
    int8_t* __restrict__ Ch, int8_t* __restrict__ Cl)
{
  __shared__ __align__(16) int8_t sAh[128 * 64];
  __shared__ __align__(16) int8_t sAl[128 * 64];
  __shared__ __align__(16) int8_t sBh[128 * 64];
  __shared__ __align__(16) int8_t sBl[128 * 64];

  const int tid  = threadIdx.x;
  const int wave = tid >> 6;
  const int lane = tid & 63;
  const int quad = lane >> 4;
  const int t16  = lane & 15;
  const int wm   = wave & 1;
  const int wn   = wave >> 1;
  const int row0 = blockIdx.y * 128;
  const int col0 = blockIdx.x * 128;

  const int seg  = lane & 3;
  const int rsub = lane >> 2;

  int4v hh[4][4], cc[4][4];
#pragma unroll
  for (int i = 0; i < 4; ++i)
#pragma unroll
    for (int j = 0; j < 4; ++j) {
      hh[i][j] = (int4v){0, 0, 0, 0};
      cc[i][j] = (int4v){0, 0, 0, 0};
    }

  for (int k0 = 0; k0 < 1024; k0 += 64) {
#pragma unroll
    for (int r = 0; r < 2; ++r) {
      const int trow = r * 64 + wave * 16;
      const size_t goffA = (size_t)(row0 + trow + rsub) * 1024 + k0 + seg * 16;
      const size_t goffB = (size_t)(col0 + trow + rsub) * 1024 + k0 + seg * 16;
      GLOAD_LDS16(Ahi + goffA, &sAh[trow * 64]);
      GLOAD_LDS16(Alo + goffA, &sAl[trow * 64]);
      GLOAD_LDS16(Bhi + goffB, &sBh[trow * 64]);
      GLOAD_LDS16(Blo + goffB, &sBl[trow * 64]);
    }
    __syncthreads();

    int4v ah[4], al[4], bh[4], bl[4];
#pragma unroll
    for (int i = 0; i < 4; ++i) {
      const int ar = (wm * 64 + i * 16 + t16) * 64 + quad * 16;
      ah[i] = *(const int4v*)&sAh[ar];
      al[i] = *(const int4v*)&sAl[ar];
    }
#pragma unroll
    for (int j = 0; j < 4; ++j) {
      const int br = (wn * 64 + j * 16 + t16) * 64 + quad * 16;
      bh[j] = *(const int4v*)&sBh[br];
      bl[j] = *(const int4v*)&sBl[br];
    }

#pragma unroll
    for (int i = 0; i < 4; ++i)
#pragma unroll
      for (int j = 0; j < 4; ++j) {
        hh[i][j] = __builtin_amdgcn_mfma_i32_16x16x64_i8(ah[i], bh[j], hh[i][j], 0, 0, 0);
        cc[i][j] = __builtin_amdgcn_mfma_i32_16x16x64_i8(ah[i], bl[j], cc[i][j], 0, 0, 0);
        cc[i][j] = __builtin_amdgcn_mfma_i32_16x16x64_i8(al[i], bh[j], cc[i][j], 0, 0, 0);
      }
    __syncthreads();
  }

#pragma unroll
  for (int i = 0; i < 4; ++i) {
#pragma unroll
    for (int j = 0; j < 4; ++j) {
      const int ccol = col0 + wn * 64 + j * 16 + t16;
      const float* bp = (ccol < 1024) ? biasQ : (biasK - 1024);
#pragma unroll
      for (int r = 0; r < 4; ++r) {
        const int crow = row0 + wm * 64 + i * 16 + quad * 4 + r;
        float v = P_HH * (float)hh[i][j][r] + P_X * (float)cc[i][j][r] + bp[ccol];
        int hi = (int)lrintf(v * INV_S256);
        hi = hi > 127 ? 127 : (hi < -127 ? -127 : hi);
        int lo = (int)lrintf(v * INV_S - 256.0f * (float)hi);
        lo = lo > 127 ? 127 : (lo < -127 ? -127 : lo);
        Ch[(size_t)crow * 2048 + ccol] = (int8_t)hi;
        Cl[(size_t)crow * 2048 + ccol] = (int8_t)lo;
      }
    }
  }
}

// ---------------------------------------------------------------------------
// AV: out += beta-scaled E x over this block's K-quarter. 256 thr, grid 1024
// = 32 bands x 8 cols x splitK=4. XCD swizzle: all 32 blocks of a band (and
// the 4 bands' (col,z) twins) share blockIdx%8 -> same XCD L2. fp32 atomicAdd
// epilogue (out zeroed by memset beforehand).
__global__ __launch_bounds__(256) void gemm_av(
    const uint16_t* __restrict__ E, const uint16_t* __restrict__ B,
    const float2* __restrict__ stats, float* __restrict__ out)
{
  __shared__ __align__(16) uint16_t sA[128 * 32];
  __shared__ __align__(16) uint16_t sB[128 * 32];
  __shared__ float betaS[128 * 33];  // stride 33 floats: conflict-free reads

  const int L      = blockIdx.x;        // 0..1023
  const int xcd    = L & 7;
  const int inner  = (L >> 3) & 31;     // 0..31 : col x z
  const int bandHi = L >> 8;            // 0..3
  const int band   = xcd + 8 * bandHi;  // 0..31
  const int colb   = inner & 7;         // 0..7
  const int z      = inner >> 3;        // 0..3
  const int row0   = band * 128;
  const int col0   = colb * 128;

  const int tid  = threadIdx.x;
  const int wave = tid >> 6;
  const int lane = tid & 63;
  const int quad = lane >> 4;
  const int t16  = lane & 15;
  const int wm   = wave & 1;
  const int wn   = wave >> 1;
  const int seg  = lane & 3;
  const int rsub = lane >> 2;

  // ---- beta prologue: threads 0..127, one row each ------------------------
  if (tid < 128) {
    const int row = row0 + tid;
    float2 st[32];
    float m = -3.0e38f;
#pragma unroll
    for (int t = 0; t < 32; ++t) {
      st[t] = stats[(size_t)row * 32 + t];
      m = fmaxf(m, st[t].x);
    }
    float l = 0.f;
#pragma unroll
    for (int t = 0; t < 32; ++t) l += st[t].y * __expf(st[t].x - m);
    const float inv = 1.0f / l;
#pragma unroll
    for (int t = 0; t < 32; ++t)
      betaS[tid * 33 + t] = __expf(st[t].x - m) * inv;
  }
  __syncthreads();

  float4v acc[4][4];
#pragma unroll
  for (int i = 0; i < 4; ++i)
#pragma unroll
    for (int j = 0; j < 4; ++j)
      acc[i][j] = (float4v){0.f, 0.f, 0.f, 0.f};

  // ---- K loop: this block covers t = z*8 .. z*8+7 (8 tiles x 128 K) -------
  for (int tt = 0; tt < 8; ++tt) {
    const int t = z * 8 + tt;
    _Float16 bb[4];
#pragma unroll
    for (int i = 0; i < 4; ++i)
      bb[i] = (_Float16)betaS[(wm * 64 + i * 16 + t16) * 33 + t];

#pragma unroll
    for (int kk = 0; kk < 4; ++kk) {
      const int k0 = t * 128 + kk * 32;
#pragma unroll
      for (int r = 0; r < 2; ++r) {
        const int trow = r * 64 + wave * 16;
        const size_t goffA = (size_t)(row0 + trow + rsub) * 4096 + k0 + seg * 8;
        const size_t goffB = (size_t)(col0 + trow + rsub) * 4096 + k0 + seg * 8;
        GLOAD_LDS16(E + goffA, &sA[trow * 32]);
        GLOAD_LDS16(B + goffB, &sB[trow * 32]);
      }
      __syncthreads();

      half8 af[4], bf[4];
#pragma unroll
      for (int i = 0; i < 4; ++i) {
        af[i] = *(const half8*)&sA[(wm * 64 + i * 16 + t16) * 32 + quad * 8];
        half8 bs;
#pragma unroll
        for (int c = 0; c < 8; ++c) bs[c] = bb[i];
        af[i] = af[i] * bs;
      }
#pragma unroll
      for (int j = 0; j < 4; ++j)
        bf[j] = *(const half8*)&sB[(wn * 64 + j * 16 + t16) * 32 + quad * 8];

#pragma unroll
      for (int i = 0; i < 4; ++i)
#pragma unroll
        for (int j = 0; j < 4; ++j)
          acc[i][j] = __builtin_amdgcn_mfma_f32_16x16x32_f16(af[i], bf[j], acc[i][j], 0, 0, 0);
      __syncthreads();
    }
  }

  // ---- atomic accumulate into out -----------------------------------------
#pragma unroll
  for (int i = 0; i < 4; ++i) {
#pragma unroll
    for (int j = 0; j < 4; ++j) {
      const int ccol = col0 + wn * 64 + j * 16 + t16;
#pragma unroll
      for (int r = 0; r < 4; ++r) {
        const int crow = row0 + wm * 64 + i * 16 + quad * 4 + r;
        atomicAdd(&out[(size_t)crow * 1024 + ccol], acc[i][j][r]);
      }
    }
  }
}

// ---------------------------------------------------------------------------
// Fused quant + transpose-cast (R9-verified).
__global__ __launch_bounds__(256) void quantT(
    const float* __restrict__ x, const float* __restrict__ Wq,
    const float* __restrict__ Wk,
    int8_t* __restrict__ xhi, int8_t* __restrict__ xlo,
    int8_t* __restrict__ whi, int8_t* __restrict__ wlo,
    uint16_t* __restrict__ xT)
{
  if (blockIdx.x < 6144) {
    int i = blockIdx.x * 256 + threadIdx.x;  // 0..1572863
    const float* src; int8_t* dh; int8_t* dl; int idx; float s256, s;
    if (i < 1048576)      { src = x;  idx = i;           dh = xhi; dl = xlo;
                            s256 = INV_S256; s = INV_S; }
    else if (i < 1310720) { src = Wq; idx = i - 1048576; dh = whi; dl = wlo;
                            s256 = 512.0f; s = 131072.0f; }
    else                  { src = Wk; idx = i - 1310720; dh = whi + 1048576;
                            dl = wlo + 1048576; s256 = 512.0f; s = 131072.0f; }
    float4 v = ((const float4*)src)[idx];
    float vv[4] = {v.x, v.y, v.z, v.w};
    int hp = 0, lp = 0;
#pragma unroll
    for (int c = 0; c < 4; ++c) {
      int h = (int)lrintf(vv[c] * s256);
      h = h > 127 ? 127 : (h < -127 ? -127 : h);
      int l = (int)lrintf(vv[c] * s - 256.0f * (float)h);
      l = l > 127 ? 127 : (l < -127 ? -127 : l);
      hp |= (h & 0xff) << (8 * c);
      lp |= (l & 0xff) << (8 * c);
    }
    ((int*)dh)[idx] = hp;
    ((int*)dl)[idx] = lp;
  } else {
    __shared__ float tile[32][33];
    const int tb = blockIdx.x - 6144;   // 0..4095
    const int bx = tb & 31;             // D/32
    const int by = tb >> 5;             // N/32
    const int tx = threadIdx.x & 31;
    const int ty = threadIdx.x >> 5;    // 0..7
#pragma unroll
    for (int p = 0; p < 4; ++p) {
      const int row = by * 32 + ty + p * 8;
      tile[ty + p * 8][tx] = x[(size_t)row * 1024 + bx * 32 + tx];
    }
    __syncthreads();
#pragma unroll
    for (int p = 0; p < 4; ++p) {
      const int oc = ty + p * 8;
      __half hv = __float2half_rn(tile[tx][oc]);
      xT[(size_t)(bx * 32 + oc) * 4096 + by * 32 + tx] = *(uint16_t*)&hv;
    }
  }
}

extern "C" void kernel_launch(void* const* d_in, const int* in_sizes, int n_in,
                              void* d_out, int out_size, void* d_ws, size_t ws_size,
                              hipStream_t stream) {
  const int N = 4096, D = 1024;
  const float* x  = (const float*)d_in[0];
  const float* Wq = (const float*)d_in[1];
  const float* bq = (const float*)d_in[2];
  const float* Wk = (const float*)d_in[3];
  const float* bk = (const float*)d_in[4];
  float* out = (float*)d_out;

  // workspace layout (MiB offsets)
  char* w = (char*)d_ws;
  const size_t MiB = 1024 * 1024;
  int8_t*    xq_hi  = (int8_t*)   (w + 0  * MiB);  // [N x D]
  int8_t*    xq_lo  = (int8_t*)   (w + 4  * MiB);
  int8_t*    Wqk_hi = (int8_t*)   (w + 8  * MiB);  // [2048 x D]
  int8_t*    Wqk_lo = (int8_t*)   (w + 10 * MiB);
  int8_t*    qk_hi  = (int8_t*)   (w + 12 * MiB);  // [N x 2048]
  int8_t*    qk_lo  = (int8_t*)   (w + 20 * MiB);
  _Float16*  E      = (_Float16*) (w + 36 * MiB);  // [N x N] fp16, 32 MiB
  float2*    stats  = (float2*)   (w + 68 * MiB);  // [N x 32] (m,l), 1 MiB
  uint16_t*  xTh    = (uint16_t*) (w + 72 * MiB);  // [D x N] fp16
  // total 80 MiB

  // 0) zero out for the atomic AV reduction
  hipMemsetAsync(out, 0, (size_t)N * D * sizeof(float), stream);

  // 1) fused quantization + transpose-cast  (6144 + 4096 blocks)
  quantT<<<10240, 256, 0, stream>>>(x, Wq, Wk, xq_hi, xq_lo, Wqk_hi, Wqk_lo,
                                    xTh);

  // 2) fused qk projection: i8 16x16x64, 3-MFMA, bias+quant epilogue
  gemm_proj_i8<<<dim3(2048 / 128, N / 128), 256, 0, stream>>>(
      xq_hi, xq_lo, Wqk_hi, Wqk_lo, bq, bk, qk_hi, qk_lo);

  // 3) S = q k^T + tile softmax stats -> E fp16, stats (m_t, l_t)
  gemm_s_stats<<<dim3(N / 128, N / 128), 256, 0, stream>>>(
      qk_hi, qk_lo, qk_hi + 1024, qk_lo + 1024, E, stats);

  // 4) out += sum_t beta_t (E_t x): 32 bands x 8 cols x splitK=4, atomicAdd
  gemm_av<<<1024, 256, 0, stream>>>((const uint16_t*)E, xTh, stats, out);

  (void)in_sizes; (void)n_in; (void)out_size; (void)ws_size;
}

// Round 11
// 244.243 us; speedup vs baseline: 1.1283x; 1.1283x over previous
//
#include <hip/hip_runtime.h>
#include <hip/hip_bf16.h>
#include <hip/hip_fp16.h>
#include <stdint.h>

// ---------------------------------------------------------------------------
// CLIPAttentionPooling. R11: revert R10's atomic AV (cross-XCD atomic RMW =
// 128 MB memory-side traffic, 100 us). New AV: 128x64 tile, FULL K=4096 per
// block (no reduction), grid 512 = 32 bands x 16 col-slabs, BK=64 (16 MFMA
// per barrier-pair), beta from stats in prologue, direct fp32 store.
// quantT / proj / S unchanged (R8/R9-verified). 4 dispatches.
// ---------------------------------------------------------------------------

using half8   = __attribute__((ext_vector_type(8))) _Float16;
using float4v = __attribute__((ext_vector_type(4))) float;
using int4v   = __attribute__((ext_vector_type(4))) int;

// q/k int16 grid: covers +-6.0, v = QS*(256*hi+lo)
#define QS        (6.0f / 32768.0f)
#define INV_S     (32768.0f / 6.0f)
#define INV_S256  (128.0f / 6.0f)
#define C_HH      (65536.0f * QS * QS)
#define C_X       (256.0f * QS * QS)

// x grid: +-6.0 ; W grid: +-0.25
#define SX        (6.0f / 32768.0f)
#define SW        (0.25f / 32768.0f)
#define P_HH      (65536.0f * SX * SW)
#define P_X       (256.0f * SX * SW)

#define GLOAD_LDS16(gptr, ldsptr)                                              \
  __builtin_amdgcn_global_load_lds(                                            \
      (__attribute__((address_space(1))) void*)(uintptr_t)(gptr),              \
      (__attribute__((address_space(3))) void*)(unsigned)(uintptr_t)(ldsptr),  \
      16, 0, 0)

// ---------------------------------------------------------------------------
// S GEMM + tile softmax stats. Split-i8 16x16x64, 128x128 tile, BK=64.
__global__ __launch_bounds__(256, 2) void gemm_s_stats(
    const int8_t* __restrict__ Ahi, const int8_t* __restrict__ Alo,
    const int8_t* __restrict__ Bhi, const int8_t* __restrict__ Blo,
    _Float16* __restrict__ E, float2* __restrict__ stats)
{
  __shared__ __align__(16) int8_t sAh[128 * 64];
  __shared__ __align__(16) int8_t sAl[128 * 64];
  __shared__ __align__(16) int8_t sBh[128 * 64];
  __shared__ __align__(16) int8_t sBl[128 * 64];

  const int tid  = threadIdx.x;
  const int wave = tid >> 6;
  const int lane = tid & 63;
  const int quad = lane >> 4;
  const int t16  = lane & 15;
  const int wm   = wave & 1;
  const int wn   = wave >> 1;
  const int row0 = blockIdx.y * 128;
  const int col0 = blockIdx.x * 128;

  const int seg  = lane & 3;
  const int rsub = lane >> 2;

  int4v hh[4][4], cc[4][4];
#pragma unroll
  for (int i = 0; i < 4; ++i)
#pragma unroll
    for (int j = 0; j < 4; ++j) {
      hh[i][j] = (int4v){0, 0, 0, 0};
      cc[i][j] = (int4v){0, 0, 0, 0};
    }

  for (int k0 = 0; k0 < 1024; k0 += 64) {
#pragma unroll
    for (int r = 0; r < 2; ++r) {
      const int trow = r * 64 + wave * 16;
      const size_t goffA = (size_t)(row0 + trow + rsub) * 2048 + k0 + seg * 16;
      const size_t goffB = (size_t)(col0 + trow + rsub) * 2048 + k0 + seg * 16;
      GLOAD_LDS16(Ahi + goffA, &sAh[trow * 64]);
      GLOAD_LDS16(Alo + goffA, &sAl[trow * 64]);
      GLOAD_LDS16(Bhi + goffB, &sBh[trow * 64]);
      GLOAD_LDS16(Blo + goffB, &sBl[trow * 64]);
    }
    __syncthreads();

    int4v ah[4], al[4], bh[4], bl[4];
#pragma unroll
    for (int i = 0; i < 4; ++i) {
      const int ar = (wm * 64 + i * 16 + t16) * 64 + quad * 16;
      ah[i] = *(const int4v*)&sAh[ar];
      al[i] = *(const int4v*)&sAl[ar];
    }
#pragma unroll
    for (int j = 0; j < 4; ++j) {
      const int br = (wn * 64 + j * 16 + t16) * 64 + quad * 16;
      bh[j] = *(const int4v*)&sBh[br];
      bl[j] = *(const int4v*)&sBl[br];
    }

#pragma unroll
    for (int i = 0; i < 4; ++i)
#pragma unroll
      for (int j = 0; j < 4; ++j) {
        hh[i][j] = __builtin_amdgcn_mfma_i32_16x16x64_i8(ah[i], bh[j], hh[i][j], 0, 0, 0);
        cc[i][j] = __builtin_amdgcn_mfma_i32_16x16x64_i8(ah[i], bl[j], cc[i][j], 0, 0, 0);
        cc[i][j] = __builtin_amdgcn_mfma_i32_16x16x64_i8(al[i], bh[j], cc[i][j], 0, 0, 0);
      }
    __syncthreads();
  }

  // ---- epilogue: tile-local softmax stats (R8-verified) --------------------
  float* red = (float*)sAh;

  float vv[4][4][4];
  float rmax[4][4];
#pragma unroll
  for (int i = 0; i < 4; ++i)
#pragma unroll
    for (int r = 0; r < 4; ++r) {
      float mx = -3.0e38f;
#pragma unroll
      for (int j = 0; j < 4; ++j) {
        float v = C_HH * (float)hh[i][j][r] + C_X * (float)cc[i][j][r];
        vv[i][j][r] = v;
        mx = fmaxf(mx, v);
      }
      mx = fmaxf(mx, __shfl_xor(mx, 1));
      mx = fmaxf(mx, __shfl_xor(mx, 2));
      mx = fmaxf(mx, __shfl_xor(mx, 4));
      mx = fmaxf(mx, __shfl_xor(mx, 8));
      rmax[i][r] = mx;
    }
  if (t16 == 0) {
#pragma unroll
    for (int i = 0; i < 4; ++i)
#pragma unroll
      for (int r = 0; r < 4; ++r)
        red[wn * 128 + wm * 64 + i * 16 + quad * 4 + r] = rmax[i][r];
  }
  __syncthreads();

  float mrow[4][4];
#pragma unroll
  for (int i = 0; i < 4; ++i)
#pragma unroll
    for (int r = 0; r < 4; ++r) {
      const int row = wm * 64 + i * 16 + quad * 4 + r;
      mrow[i][r] = fmaxf(red[row], red[128 + row]);
    }

  float rsum[4][4];
#pragma unroll
  for (int i = 0; i < 4; ++i)
#pragma unroll
    for (int r = 0; r < 4; ++r) {
      float s = 0.f;
#pragma unroll
      for (int j = 0; j < 4; ++j) {
        float e = __expf(vv[i][j][r] - mrow[i][r]);
        vv[i][j][r] = e;
        s += e;
      }
      s += __shfl_xor(s, 1);
      s += __shfl_xor(s, 2);
      s += __shfl_xor(s, 4);
      s += __shfl_xor(s, 8);
      rsum[i][r] = s;
    }
  if (t16 == 0) {
#pragma unroll
    for (int i = 0; i < 4; ++i)
#pragma unroll
      for (int r = 0; r < 4; ++r)
        red[256 + wn * 128 + wm * 64 + i * 16 + quad * 4 + r] = rsum[i][r];
  }
  __syncthreads();

#pragma unroll
  for (int i = 0; i < 4; ++i) {
#pragma unroll
    for (int j = 0; j < 4; ++j) {
#pragma unroll
      for (int r = 0; r < 4; ++r) {
        const int crow = row0 + wm * 64 + i * 16 + quad * 4 + r;
        const int ccol = col0 + wn * 64 + j * 16 + t16;
        E[(size_t)crow * 4096 + ccol] = (_Float16)vv[i][j][r];
      }
    }
  }
  if (wn == 0 && t16 == 0) {
#pragma unroll
    for (int i = 0; i < 4; ++i)
#pragma unroll
      for (int r = 0; r < 4; ++r) {
        const int row = wm * 64 + i * 16 + quad * 4 + r;
        const float l = red[256 + row] + red[256 + 128 + row];
        stats[(size_t)(row0 + row) * 32 + blockIdx.x] =
            make_float2(mrow[i][r], l);
      }
  }
}

// ---------------------------------------------------------------------------
// proj: qk = x Wqk^T + bias, split-i8 3-MFMA, bias + int16-grid quant epilogue.
__global__ __launch_bounds__(256, 2) void gemm_proj_i8(
    const int8_t* __restrict__ Ahi, const int8_t* __restrict__ Alo,
    const int8_t* __restrict__ Bhi, const int8_t* __restrict__ Blo,
    const float* __restrict__ biasQ, const float* __restrict__ biasK,
    int8_t* __restrict__ Ch, int8_t* __restrict__ Cl)
{
  __shared__ __align__(16) int8_t sAh[128 * 64];
  __shared__ __align__(16) int8_t sAl[128 * 64];
  __shared__ __align__(16) int8_t sBh[128 * 64];
  __shared__ __align__(16) int8_t sBl[128 * 64];

  const int tid  = threadIdx.x;
  const int wave = tid >> 6;
  const int lane = tid & 63;
  const int quad = lane >> 4;
  const int t16  = lane & 15;
  const int wm   = wave & 1;
  const int wn   = wave >> 1;
  const int row0 = blockIdx.y * 128;
  const int col0 = blockIdx.x * 128;

  const int seg  = lane & 3;
  const int rsub = lane >> 2;

  int4v hh[4][4], cc[4][4];
#pragma unroll
  for (int i = 0; i < 4; ++i)
#pragma unroll
    for (int j = 0; j < 4; ++j) {
      hh[i][j] = (int4v){0, 0, 0, 0};
      cc[i][j] = (int4v){0, 0, 0, 0};
    }

  for (int k0 = 0; k0 < 1024; k0 += 64) {
#pragma unroll
    for (int r = 0; r < 2; ++r) {
      const int trow = r * 64 + wave * 16;
      const size_t goffA = (size_t)(row0 + trow + rsub) * 1024 + k0 + seg * 16;
      const size_t goffB = (size_t)(col0 + trow + rsub) * 1024 + k0 + seg * 16;
      GLOAD_LDS16(Ahi + goffA, &sAh[trow * 64]);
      GLOAD_LDS16(Alo + goffA, &sAl[trow * 64]);
      GLOAD_LDS16(Bhi + goffB, &sBh[trow * 64]);
      GLOAD_LDS16(Blo + goffB, &sBl[trow * 64]);
    }
    __syncthreads();

    int4v ah[4], al[4], bh[4], bl[4];
#pragma unroll
    for (int i = 0; i < 4; ++i) {
      const int ar = (wm * 64 + i * 16 + t16) * 64 + quad * 16;
      ah[i] = *(const int4v*)&sAh[ar];
      al[i] = *(const int4v*)&sAl[ar];
    }
#pragma unroll
    for (int j = 0; j < 4; ++j) {
      const int br = (wn * 64 + j * 16 + t16) * 64 + quad * 16;
      bh[j] = *(const int4v*)&sBh[br];
      bl[j] = *(const int4v*)&sBl[br];
    }

#pragma unroll
    for (int i = 0; i < 4; ++i)
#pragma unroll
      for (int j = 0; j < 4; ++j) {
        hh[i][j] = __builtin_amdgcn_mfma_i32_16x16x64_i8(ah[i], bh[j], hh[i][j], 0, 0, 0);
        cc[i][j] = __builtin_amdgcn_mfma_i32_16x16x64_i8(ah[i], bl[j], cc[i][j], 0, 0, 0);
        cc[i][j] = __builtin_amdgcn_mfma_i32_16x16x64_i8(al[i], bh[j], cc[i][j], 0, 0, 0);
      }
    __syncthreads();
  }

#pragma unroll
  for (int i = 0; i < 4; ++i) {
#pragma unroll
    for (int j = 0; j < 4; ++j) {
      const int ccol = col0 + wn * 64 + j * 16 + t16;
      const float* bp = (ccol < 1024) ? biasQ : (biasK - 1024);
#pragma unroll
      for (int r = 0; r < 4; ++r) {
        const int crow = row0 + wm * 64 + i * 16 + quad * 4 + r;
        float v = P_HH * (float)hh[i][j][r] + P_X * (float)cc[i][j][r] + bp[ccol];
        int hi = (int)lrintf(v * INV_S256);
        hi = hi > 127 ? 127 : (hi < -127 ? -127 : hi);
        int lo = (int)lrintf(v * INV_S - 256.0f * (float)hi);
        lo = lo > 127 ? 127 : (lo < -127 ? -127 : lo);
        Ch[(size_t)crow * 2048 + ccol] = (int8_t)hi;
        Cl[(size_t)crow * 2048 + ccol] = (int8_t)lo;
      }
    }
  }
}

// ---------------------------------------------------------------------------
// AV: out = sum_t beta_t (E_t x). 128x64 tile, FULL K=4096 per block (no
// reduction). Grid 512 = 32 bands x 16 col-slabs; XCD swizzle: all 16 blocks
// of a band share blockIdx%8 -> band's E slice stays in one XCD's L2.
// BK=64: 16 MFMA per wave per barrier-pair. Direct fp32 store.
__global__ __launch_bounds__(256) void gemm_av(
    const uint16_t* __restrict__ E, const uint16_t* __restrict__ B,
    const float2* __restrict__ stats, float* __restrict__ out)
{
  __shared__ __align__(16) uint16_t sA[128 * 64];  // 16 KB
  __shared__ __align__(16) uint16_t sB[64 * 64];   //  8 KB
  __shared__ float betaS[128 * 33];                // 16.9 KB, conflict-free

  const int L      = blockIdx.x;        // 0..511
  const int xcd    = L & 7;
  const int rest   = L >> 3;            // 0..63
  const int colb   = rest & 15;         // 0..15
  const int bandHi = rest >> 4;         // 0..3
  const int band   = xcd + 8 * bandHi;  // 0..31
  const int row0   = band * 128;
  const int col0   = colb * 64;

  const int tid  = threadIdx.x;
  const int wave = tid >> 6;
  const int lane = tid & 63;
  const int quad = lane >> 4;
  const int t16  = lane & 15;
  const int wm   = wave & 1;            // 64-row half
  const int wn   = wave >> 1;           // 32-col half
  const int seg  = lane & 7;            // 16B segment in a 128B row
  const int rsub = lane >> 3;           // 8 rows per wave pass

  // ---- beta prologue: threads 0..127, one row each ------------------------
  if (tid < 128) {
    const int row = row0 + tid;
    float2 st[32];
    float m = -3.0e38f;
#pragma unroll
    for (int t = 0; t < 32; ++t) {
      st[t] = stats[(size_t)row * 32 + t];
      m = fmaxf(m, st[t].x);
    }
    float l = 0.f;
#pragma unroll
    for (int t = 0; t < 32; ++t) l += st[t].y * __expf(st[t].x - m);
    const float inv = 1.0f / l;
#pragma unroll
    for (int t = 0; t < 32; ++t)
      betaS[tid * 33 + t] = __expf(st[t].x - m) * inv;
  }
  __syncthreads();

  float4v acc[4][2];
#pragma unroll
  for (int i = 0; i < 4; ++i)
#pragma unroll
    for (int j = 0; j < 2; ++j)
      acc[i][j] = (float4v){0.f, 0.f, 0.f, 0.f};

  // ---- K loop: 32 beta-tiles x 2 iters of BK=64 ---------------------------
  for (int t = 0; t < 32; ++t) {
    _Float16 bb[4];
#pragma unroll
    for (int i = 0; i < 4; ++i)
      bb[i] = (_Float16)betaS[(wm * 64 + i * 16 + t16) * 33 + t];

#pragma unroll
    for (int kk = 0; kk < 2; ++kk) {
      const int k0 = t * 128 + kk * 64;
      // stage A: 128 rows x 128 B, 32 rows per pass (4 waves x 8 rows)
#pragma unroll
      for (int r = 0; r < 4; ++r) {
        const int trow = r * 32 + wave * 8;
        const size_t goffA = (size_t)(row0 + trow + rsub) * 4096 + k0 + seg * 8;
        GLOAD_LDS16(E + goffA, &sA[trow * 64]);
      }
      // stage B: 64 rows
#pragma unroll
      for (int r = 0; r < 2; ++r) {
        const int trow = r * 32 + wave * 8;
        const size_t goffB = (size_t)(col0 + trow + rsub) * 4096 + k0 + seg * 8;
        GLOAD_LDS16(B + goffB, &sB[trow * 64]);
      }
      __syncthreads();

      half8 af[4][2], bf[2][2];
#pragma unroll
      for (int i = 0; i < 4; ++i) {
        const int ar = (wm * 64 + i * 16 + t16) * 64;
        half8 bs;
#pragma unroll
        for (int c = 0; c < 8; ++c) bs[c] = bb[i];
#pragma unroll
        for (int kh = 0; kh < 2; ++kh)
          af[i][kh] = *(const half8*)&sA[ar + kh * 32 + quad * 8] * bs;
      }
#pragma unroll
      for (int j = 0; j < 2; ++j) {
        const int br = (wn * 32 + j * 16 + t16) * 64;
#pragma unroll
        for (int kh = 0; kh < 2; ++kh)
          bf[j][kh] = *(const half8*)&sB[br + kh * 32 + quad * 8];
      }

#pragma unroll
      for (int kh = 0; kh < 2; ++kh)
#pragma unroll
        for (int i = 0; i < 4; ++i)
#pragma unroll
          for (int j = 0; j < 2; ++j)
            acc[i][j] = __builtin_amdgcn_mfma_f32_16x16x32_f16(
                af[i][kh], bf[j][kh], acc[i][j], 0, 0, 0);
      __syncthreads();
    }
  }

  // ---- direct store -------------------------------------------------------
#pragma unroll
  for (int i = 0; i < 4; ++i) {
#pragma unroll
    for (int j = 0; j < 2; ++j) {
      const int ccol = col0 + wn * 32 + j * 16 + t16;
#pragma unroll
      for (int r = 0; r < 4; ++r) {
        const int crow = row0 + wm * 64 + i * 16 + quad * 4 + r;
        out[(size_t)crow * 1024 + ccol] = acc[i][j][r];
      }
    }
  }
}

// ---------------------------------------------------------------------------
// Fused quant + transpose-cast (R9-verified).
__global__ __launch_bounds__(256) void quantT(
    const float* __restrict__ x, const float* __restrict__ Wq,
    const float* __restrict__ Wk,
    int8_t* __restrict__ xhi, int8_t* __restrict__ xlo,
    int8_t* __restrict__ whi, int8_t* __restrict__ wlo,
    uint16_t* __restrict__ xT)
{
  if (blockIdx.x < 6144) {
    int i = blockIdx.x * 256 + threadIdx.x;  // 0..1572863
    const float* src; int8_t* dh; int8_t* dl; int idx; float s256, s;
    if (i < 1048576)      { src = x;  idx = i;           dh = xhi; dl = xlo;
                            s256 = INV_S256; s = INV_S; }
    else if (i < 1310720) { src = Wq; idx = i - 1048576; dh = whi; dl = wlo;
                            s256 = 512.0f; s = 131072.0f; }
    else                  { src = Wk; idx = i - 1310720; dh = whi + 1048576;
                            dl = wlo + 1048576; s256 = 512.0f; s = 131072.0f; }
    float4 v = ((const float4*)src)[idx];
    float vv[4] = {v.x, v.y, v.z, v.w};
    int hp = 0, lp = 0;
#pragma unroll
    for (int c = 0; c < 4; ++c) {
      int h = (int)lrintf(vv[c] * s256);
      h = h > 127 ? 127 : (h < -127 ? -127 : h);
      int l = (int)lrintf(vv[c] * s - 256.0f * (float)h);
      l = l > 127 ? 127 : (l < -127 ? -127 : l);
      hp |= (h & 0xff) << (8 * c);
      lp |= (l & 0xff) << (8 * c);
    }
    ((int*)dh)[idx] = hp;
    ((int*)dl)[idx] = lp;
  } else {
    __shared__ float tile[32][33];
    const int tb = blockIdx.x - 6144;   // 0..4095
    const int bx = tb & 31;             // D/32
    const int by = tb >> 5;             // N/32
    const int tx = threadIdx.x & 31;
    const int ty = threadIdx.x >> 5;    // 0..7
#pragma unroll
    for (int p = 0; p < 4; ++p) {
      const int row = by * 32 + ty + p * 8;
      tile[ty + p * 8][tx] = x[(size_t)row * 1024 + bx * 32 + tx];
    }
    __syncthreads();
#pragma unroll
    for (int p = 0; p < 4; ++p) {
      const int oc = ty + p * 8;
      __half hv = __float2half_rn(tile[tx][oc]);
      xT[(size_t)(bx * 32 + oc) * 4096 + by * 32 + tx] = *(uint16_t*)&hv;
    }
  }
}

extern "C" void kernel_launch(void* const* d_in, const int* in_sizes, int n_in,
                              void* d_out, int out_size, void* d_ws, size_t ws_size,
                              hipStream_t stream) {
  const int N = 4096, D = 1024;
  const float* x  = (const float*)d_in[0];
  const float* Wq = (const float*)d_in[1];
  const float* bq = (const float*)d_in[2];
  const float* Wk = (const float*)d_in[3];
  const float* bk = (const float*)d_in[4];
  float* out = (float*)d_out;

  // workspace layout (MiB offsets)
  char* w = (char*)d_ws;
  const size_t MiB = 1024 * 1024;
  int8_t*    xq_hi  = (int8_t*)   (w + 0  * MiB);  // [N x D]
  int8_t*    xq_lo  = (int8_t*)   (w + 4  * MiB);
  int8_t*    Wqk_hi = (int8_t*)   (w + 8  * MiB);  // [2048 x D]
  int8_t*    Wqk_lo = (int8_t*)   (w + 10 * MiB);
  int8_t*    qk_hi  = (int8_t*)   (w + 12 * MiB);  // [N x 2048]
  int8_t*    qk_lo  = (int8_t*)   (w + 20 * MiB);
  _Float16*  E      = (_Float16*) (w + 36 * MiB);  // [N x N] fp16, 32 MiB
  float2*    stats  = (float2*)   (w + 68 * MiB);  // [N x 32] (m,l), 1 MiB
  uint16_t*  xTh    = (uint16_t*) (w + 72 * MiB);  // [D x N] fp16
  // total 80 MiB

  // 1) fused quantization + transpose-cast  (6144 + 4096 blocks)
  quantT<<<10240, 256, 0, stream>>>(x, Wq, Wk, xq_hi, xq_lo, Wqk_hi, Wqk_lo,
                                    xTh);

  // 2) fused qk projection: i8 16x16x64, 3-MFMA, bias+quant epilogue
  gemm_proj_i8<<<dim3(2048 / 128, N / 128), 256, 0, stream>>>(
      xq_hi, xq_lo, Wqk_hi, Wqk_lo, bq, bk, qk_hi, qk_lo);

  // 3) S = q k^T + tile softmax stats -> E fp16, stats (m_t, l_t)
  gemm_s_stats<<<dim3(N / 128, N / 128), 256, 0, stream>>>(
      qk_hi, qk_lo, qk_hi + 1024, qk_lo + 1024, E, stats);

  // 4) out = sum_t beta_t (E_t x): 128x64 full-K blocks, direct store
  gemm_av<<<512, 256, 0, stream>>>((const uint16_t*)E, xTh, stats, out);

  (void)in_sizes; (void)n_in; (void)out_size; (void)ws_size;
}

// Round 12
// 242.784 us; speedup vs baseline: 1.1351x; 1.0060x over previous
//
#include <hip/hip_runtime.h>
#include <hip/hip_bf16.h>
#include <hip/hip_fp16.h>
#include <stdint.h>

// ---------------------------------------------------------------------------
// CLIPAttentionPooling. R12: AV rebuilt — 128x64 block tile, 4 waves =
// 2 row-halves x 2 K-groups (in-block split-K, lockstep barriers), each wave
// owns a 64x64 subtile (8 ds_read_b128 per 16 MFMA, vs R11's 12), fp16 beta
// in LDS (32.5 KB total -> 4 blocks/CU), LDS combine + direct fp32 store.
// quantT / proj / S unchanged (R8/R9-verified). 4 dispatches.
// ---------------------------------------------------------------------------

using half8   = __attribute__((ext_vector_type(8))) _Float16;
using float4v = __attribute__((ext_vector_type(4))) float;
using int4v   = __attribute__((ext_vector_type(4))) int;

// q/k int16 grid: covers +-6.0, v = QS*(256*hi+lo)
#define QS        (6.0f / 32768.0f)
#define INV_S     (32768.0f / 6.0f)
#define INV_S256  (128.0f / 6.0f)
#define C_HH      (65536.0f * QS * QS)
#define C_X       (256.0f * QS * QS)

// x grid: +-6.0 ; W grid: +-0.25
#define SX        (6.0f / 32768.0f)
#define SW        (0.25f / 32768.0f)
#define P_HH      (65536.0f * SX * SW)
#define P_X       (256.0f * SX * SW)

#define GLOAD_LDS16(gptr, ldsptr)                                              \
  __builtin_amdgcn_global_load_lds(                                            \
      (__attribute__((address_space(1))) void*)(uintptr_t)(gptr),              \
      (__attribute__((address_space(3))) void*)(unsigned)(uintptr_t)(ldsptr),  \
      16, 0, 0)

// ---------------------------------------------------------------------------
// S GEMM + tile softmax stats. Split-i8 16x16x64, 128x128 tile, BK=64.
__global__ __launch_bounds__(256, 2) void gemm_s_stats(
    const int8_t* __restrict__ Ahi, const int8_t* __restrict__ Alo,
    const int8_t* __restrict__ Bhi, const int8_t* __restrict__ Blo,
    _Float16* __restrict__ E, float2* __restrict__ stats)
{
  __shared__ __align__(16) int8_t sAh[128 * 64];
  __shared__ __align__(16) int8_t sAl[128 * 64];
  __shared__ __align__(16) int8_t sBh[128 * 64];
  __shared__ __align__(16) int8_t sBl[128 * 64];

  const int tid  = threadIdx.x;
  const int wave = tid >> 6;
  const int lane = tid & 63;
  const int quad = lane >> 4;
  const int t16  = lane & 15;
  const int wm   = wave & 1;
  const int wn   = wave >> 1;
  const int row0 = blockIdx.y * 128;
  const int col0 = blockIdx.x * 128;

  const int seg  = lane & 3;
  const int rsub = lane >> 2;

  int4v hh[4][4], cc[4][4];
#pragma unroll
  for (int i = 0; i < 4; ++i)
#pragma unroll
    for (int j = 0; j < 4; ++j) {
      hh[i][j] = (int4v){0, 0, 0, 0};
      cc[i][j] = (int4v){0, 0, 0, 0};
    }

  for (int k0 = 0; k0 < 1024; k0 += 64) {
#pragma unroll
    for (int r = 0; r < 2; ++r) {
      const int trow = r * 64 + wave * 16;
      const size_t goffA = (size_t)(row0 + trow + rsub) * 2048 + k0 + seg * 16;
      const size_t goffB = (size_t)(col0 + trow + rsub) * 2048 + k0 + seg * 16;
      GLOAD_LDS16(Ahi + goffA, &sAh[trow * 64]);
      GLOAD_LDS16(Alo + goffA, &sAl[trow * 64]);
      GLOAD_LDS16(Bhi + goffB, &sBh[trow * 64]);
      GLOAD_LDS16(Blo + goffB, &sBl[trow * 64]);
    }
    __syncthreads();

    int4v ah[4], al[4], bh[4], bl[4];
#pragma unroll
    for (int i = 0; i < 4; ++i) {
      const int ar = (wm * 64 + i * 16 + t16) * 64 + quad * 16;
      ah[i] = *(const int4v*)&sAh[ar];
      al[i] = *(const int4v*)&sAl[ar];
    }
#pragma unroll
    for (int j = 0; j < 4; ++j) {
      const int br = (wn * 64 + j * 16 + t16) * 64 + quad * 16;
      bh[j] = *(const int4v*)&sBh[br];
      bl[j] = *(const int4v*)&sBl[br];
    }

#pragma unroll
    for (int i = 0; i < 4; ++i)
#pragma unroll
      for (int j = 0; j < 4; ++j) {
        hh[i][j] = __builtin_amdgcn_mfma_i32_16x16x64_i8(ah[i], bh[j], hh[i][j], 0, 0, 0);
        cc[i][j] = __builtin_amdgcn_mfma_i32_16x16x64_i8(ah[i], bl[j], cc[i][j], 0, 0, 0);
        cc[i][j] = __builtin_amdgcn_mfma_i32_16x16x64_i8(al[i], bh[j], cc[i][j], 0, 0, 0);
      }
    __syncthreads();
  }

  // ---- epilogue: tile-local softmax stats (R8-verified) --------------------
  float* red = (float*)sAh;

  float vv[4][4][4];
  float rmax[4][4];
#pragma unroll
  for (int i = 0; i < 4; ++i)
#pragma unroll
    for (int r = 0; r < 4; ++r) {
      float mx = -3.0e38f;
#pragma unroll
      for (int j = 0; j < 4; ++j) {
        float v = C_HH * (float)hh[i][j][r] + C_X * (float)cc[i][j][r];
        vv[i][j][r] = v;
        mx = fmaxf(mx, v);
      }
      mx = fmaxf(mx, __shfl_xor(mx, 1));
      mx = fmaxf(mx, __shfl_xor(mx, 2));
      mx = fmaxf(mx, __shfl_xor(mx, 4));
      mx = fmaxf(mx, __shfl_xor(mx, 8));
      rmax[i][r] = mx;
    }
  if (t16 == 0) {
#pragma unroll
    for (int i = 0; i < 4; ++i)
#pragma unroll
      for (int r = 0; r < 4; ++r)
        red[wn * 128 + wm * 64 + i * 16 + quad * 4 + r] = rmax[i][r];
  }
  __syncthreads();

  float mrow[4][4];
#pragma unroll
  for (int i = 0; i < 4; ++i)
#pragma unroll
    for (int r = 0; r < 4; ++r) {
      const int row = wm * 64 + i * 16 + quad * 4 + r;
      mrow[i][r] = fmaxf(red[row], red[128 + row]);
    }

  float rsum[4][4];
#pragma unroll
  for (int i = 0; i < 4; ++i)
#pragma unroll
    for (int r = 0; r < 4; ++r) {
      float s = 0.f;
#pragma unroll
      for (int j = 0; j < 4; ++j) {
        float e = __expf(vv[i][j][r] - mrow[i][r]);
        vv[i][j][r] = e;
        s += e;
      }
      s += __shfl_xor(s, 1);
      s += __shfl_xor(s, 2);
      s += __shfl_xor(s, 4);
      s += __shfl_xor(s, 8);
      rsum[i][r] = s;
    }
  if (t16 == 0) {
#pragma unroll
    for (int i = 0; i < 4; ++i)
#pragma unroll
      for (int r = 0; r < 4; ++r)
        red[256 + wn * 128 + wm * 64 + i * 16 + quad * 4 + r] = rsum[i][r];
  }
  __syncthreads();

#pragma unroll
  for (int i = 0; i < 4; ++i) {
#pragma unroll
    for (int j = 0; j < 4; ++j) {
#pragma unroll
      for (int r = 0; r < 4; ++r) {
        const int crow = row0 + wm * 64 + i * 16 + quad * 4 + r;
        const int ccol = col0 + wn * 64 + j * 16 + t16;
        E[(size_t)crow * 4096 + ccol] = (_Float16)vv[i][j][r];
      }
    }
  }
  if (wn == 0 && t16 == 0) {
#pragma unroll
    for (int i = 0; i < 4; ++i)
#pragma unroll
      for (int r = 0; r < 4; ++r) {
        const int row = wm * 64 + i * 16 + quad * 4 + r;
        const float l = red[256 + row] + red[256 + 128 + row];
        stats[(size_t)(row0 + row) * 32 + blockIdx.x] =
            make_float2(mrow[i][r], l);
      }
  }
}

// ---------------------------------------------------------------------------
// proj: qk = x Wqk^T + bias, split-i8 3-MFMA, bias + int16-grid quant epilogue.
__global__ __launch_bounds__(256, 2) void gemm_proj_i8(
    const int8_t* __restrict__ Ahi, const int8_t* __restrict__ Alo,
    const int8_t* __restrict__ Bhi, const int8_t* __restrict__ Blo,
    const float* __restrict__ biasQ, const float* __restrict__ biasK,
    int8_t* __restrict__ Ch, int8_t* __restrict__ Cl)
{
  __shared__ __align__(16) int8_t sAh[128 * 64];
  __shared__ __align__(16) int8_t sAl[128 * 64];
  __shared__ __align__(16) int8_t sBh[128 * 64];
  __shared__ __align__(16) int8_t sBl[128 * 64];

  const int tid  = threadIdx.x;
  const int wave = tid >> 6;
  const int lane = tid & 63;
  const int quad = lane >> 4;
  const int t16  = lane & 15;
  const int wm   = wave & 1;
  const int wn   = wave >> 1;
  const int row0 = blockIdx.y * 128;
  const int col0 = blockIdx.x * 128;

  const int seg  = lane & 3;
  const int rsub = lane >> 2;

  int4v hh[4][4], cc[4][4];
#pragma unroll
  for (int i = 0; i < 4; ++i)
#pragma unroll
    for (int j = 0; j < 4; ++j) {
      hh[i][j] = (int4v){0, 0, 0, 0};
      cc[i][j] = (int4v){0, 0, 0, 0};
    }

  for (int k0 = 0; k0 < 1024; k0 += 64) {
#pragma unroll
    for (int r = 0; r < 2; ++r) {
      const int trow = r * 64 + wave * 16;
      const size_t goffA = (size_t)(row0 + trow + rsub) * 1024 + k0 + seg * 16;
      const size_t goffB = (size_t)(col0 + trow + rsub) * 1024 + k0 + seg * 16;
      GLOAD_LDS16(Ahi + goffA, &sAh[trow * 64]);
      GLOAD_LDS16(Alo + goffA, &sAl[trow * 64]);
      GLOAD_LDS16(Bhi + goffB, &sBh[trow * 64]);
      GLOAD_LDS16(Blo + goffB, &sBl[trow * 64]);
    }
    __syncthreads();

    int4v ah[4], al[4], bh[4], bl[4];
#pragma unroll
    for (int i = 0; i < 4; ++i) {
      const int ar = (wm * 64 + i * 16 + t16) * 64 + quad * 16;
      ah[i] = *(const int4v*)&sAh[ar];
      al[i] = *(const int4v*)&sAl[ar];
    }
#pragma unroll
    for (int j = 0; j < 4; ++j) {
      const int br = (wn * 64 + j * 16 + t16) * 64 + quad * 16;
      bh[j] = *(const int4v*)&sBh[br];
      bl[j] = *(const int4v*)&sBl[br];
    }

#pragma unroll
    for (int i = 0; i < 4; ++i)
#pragma unroll
      for (int j = 0; j < 4; ++j) {
        hh[i][j] = __builtin_amdgcn_mfma_i32_16x16x64_i8(ah[i], bh[j], hh[i][j], 0, 0, 0);
        cc[i][j] = __builtin_amdgcn_mfma_i32_16x16x64_i8(ah[i], bl[j], cc[i][j], 0, 0, 0);
        cc[i][j] = __builtin_amdgcn_mfma_i32_16x16x64_i8(al[i], bh[j], cc[i][j], 0, 0, 0);
      }
    __syncthreads();
  }

#pragma unroll
  for (int i = 0; i < 4; ++i) {
#pragma unroll
    for (int j = 0; j < 4; ++j) {
      const int ccol = col0 + wn * 64 + j * 16 + t16;
      const float* bp = (ccol < 1024) ? biasQ : (biasK - 1024);
#pragma unroll
      for (int r = 0; r < 4; ++r) {
        const int crow = row0 + wm * 64 + i * 16 + quad * 4 + r;
        float v = P_HH * (float)hh[i][j][r] + P_X * (float)cc[i][j][r] + bp[ccol];
        int hi = (int)lrintf(v * INV_S256);
        hi = hi > 127 ? 127 : (hi < -127 ? -127 : hi);
        int lo = (int)lrintf(v * INV_S - 256.0f * (float)hi);
        lo = lo > 127 ? 127 : (lo < -127 ? -127 : lo);
        Ch[(size_t)crow * 2048 + ccol] = (int8_t)hi;
        Cl[(size_t)crow * 2048 + ccol] = (int8_t)lo;
      }
    }
  }
}

// ---------------------------------------------------------------------------
// AV: out = sum_t beta_t (E_t x). 128x64 block tile; 4 waves = 2 row-halves
// (wm) x 2 K-groups (kg, each covering K=2048). Each wave owns a 64x64
// subtile: 4x4 acc, 8 ds_read_b128 per 16 MFMA. Lockstep barriers; fp16 beta
// in LDS; 16 KB LDS combine of kg=1 into kg=0; direct fp32 store.
// Grid 512 = 32 bands x 16 col-slabs; XCD swizzle: band's E slice on one XCD.
__global__ __launch_bounds__(256) void gemm_av(
    const uint16_t* __restrict__ E, const uint16_t* __restrict__ B,
    const float2* __restrict__ stats, float* __restrict__ out)
{
  // stage carve-up (uint16 elems): sA g0 [0,4096) g1 [4096,8192),
  // sB g0 [8192,10240) g1 [10240,12288).  24 KB total.
  __shared__ __align__(16) uint16_t stage[12288];
  __shared__ _Float16 betaS[128 * 33];  // 8.4 KB fp16, stride 33

  const int L      = blockIdx.x;        // 0..511
  const int xcd    = L & 7;
  const int rest   = L >> 3;            // 0..63
  const int colb   = rest & 15;         // 0..15
  const int bandHi = rest >> 4;         // 0..3
  const int band   = xcd + 8 * bandHi;  // 0..31
  const int row0   = band * 128;
  const int col0   = colb * 64;

  const int tid  = threadIdx.x;
  const int wave = tid >> 6;
  const int kg   = wave >> 1;   // K-group (0: k<2048, 1: k>=2048)
  const int wm   = wave & 1;    // row half
  const int lane = tid & 63;
  const int quad = lane >> 4;
  const int t16  = lane & 15;
  const int seg  = lane & 3;
  const int rsub = lane >> 2;

  // ---- beta prologue: threads 0..127, one row each ------------------------
  if (tid < 128) {
    const int row = row0 + tid;
    float2 st[32];
    float m = -3.0e38f;
#pragma unroll
    for (int t = 0; t < 32; ++t) {
      st[t] = stats[(size_t)row * 32 + t];
      m = fmaxf(m, st[t].x);
    }
    float l = 0.f;
#pragma unroll
    for (int t = 0; t < 32; ++t) l += st[t].y * __expf(st[t].x - m);
    const float inv = 1.0f / l;
#pragma unroll
    for (int t = 0; t < 32; ++t)
      betaS[tid * 33 + t] = (_Float16)(__expf(st[t].x - m) * inv);
  }
  __syncthreads();

  uint16_t* sAg = &stage[kg * 4096];
  uint16_t* sBg = &stage[8192 + kg * 2048];

  float4v acc[4][4];
#pragma unroll
  for (int i = 0; i < 4; ++i)
#pragma unroll
    for (int j = 0; j < 4; ++j)
      acc[i][j] = (float4v){0.f, 0.f, 0.f, 0.f};

  _Float16 bb[4];

  // ---- K loop: 64 iters x K32 per group (groups in lockstep) --------------
  for (int it = 0; it < 64; ++it) {
    if ((it & 3) == 0) {
      const int t = kg * 16 + (it >> 2);
#pragma unroll
      for (int i = 0; i < 4; ++i)
        bb[i] = betaS[(wm * 64 + i * 16 + t16) * 33 + t];
    }

    // staging: 24 passes (16 A + 8 B), 6 per wave, all wave-uniform bases
#pragma unroll
    for (int r = 0; r < 6; ++r) {
      const int p = wave * 6 + r;
      if (p < 16) {
        const int g    = p >> 3;
        const int trow = (p & 7) * 16;
        const int k0   = g * 2048 + it * 32;
        const size_t goff = (size_t)(row0 + trow + rsub) * 4096 + k0 + seg * 8;
        GLOAD_LDS16(E + goff, &stage[g * 4096 + trow * 32]);
      } else {
        const int q    = p - 16;
        const int g    = q >> 2;
        const int trow = (q & 3) * 16;
        const int k0   = g * 2048 + it * 32;
        const size_t goff = (size_t)(col0 + trow + rsub) * 4096 + k0 + seg * 8;
        GLOAD_LDS16(B + goff, &stage[8192 + g * 2048 + trow * 32]);
      }
    }
    __syncthreads();

    half8 af[4], bf[4];
#pragma unroll
    for (int i = 0; i < 4; ++i) {
      half8 bs;
#pragma unroll
      for (int c = 0; c < 8; ++c) bs[c] = bb[i];
      af[i] = *(const half8*)&sAg[(wm * 64 + i * 16 + t16) * 32 + quad * 8] * bs;
    }
#pragma unroll
    for (int j = 0; j < 4; ++j)
      bf[j] = *(const half8*)&sBg[(j * 16 + t16) * 32 + quad * 8];

#pragma unroll
    for (int i = 0; i < 4; ++i)
#pragma unroll
      for (int j = 0; j < 4; ++j)
        acc[i][j] = __builtin_amdgcn_mfma_f32_16x16x32_f16(af[i], bf[j], acc[i][j], 0, 0, 0);
    __syncthreads();
  }

  // ---- combine kg=1 into kg=0 via LDS (2 halves x 16 KB) ------------------
  float* xfer = (float*)stage;  // 6144 floats available, 4096 used per pass
#pragma unroll
  for (int h = 0; h < 2; ++h) {
    if (kg == 1) {
#pragma unroll
      for (int ii = 0; ii < 2; ++ii)
#pragma unroll
        for (int j = 0; j < 4; ++j)
#pragma unroll
          for (int r = 0; r < 4; ++r)
            xfer[wm * 2048 + ((ii * 4 + j) * 4 + r) * 64 + lane] =
                acc[2 * h + ii][j][r];
    }
    __syncthreads();
    if (kg == 0) {
#pragma unroll
      for (int ii = 0; ii < 2; ++ii)
#pragma unroll
        for (int j = 0; j < 4; ++j)
#pragma unroll
          for (int r = 0; r < 4; ++r)
            acc[2 * h + ii][j][r] +=
                xfer[wm * 2048 + ((ii * 4 + j) * 4 + r) * 64 + lane];
    }
    __syncthreads();
  }

  // ---- direct store (kg = 0) ----------------------------------------------
  if (kg == 0) {
#pragma unroll
    for (int i = 0; i < 4; ++i) {
#pragma unroll
      for (int j = 0; j < 4; ++j) {
        const int ccol = col0 + j * 16 + t16;
#pragma unroll
        for (int r = 0; r < 4; ++r) {
          const int crow = row0 + wm * 64 + i * 16 + quad * 4 + r;
          out[(size_t)crow * 1024 + ccol] = acc[i][j][r];
        }
      }
    }
  }
}

// ---------------------------------------------------------------------------
// Fused quant + transpose-cast (R9-verified).
__global__ __launch_bounds__(256) void quantT(
    const float* __restrict__ x, const float* __restrict__ Wq,
    const float* __restrict__ Wk,
    int8_t* __restrict__ xhi, int8_t* __restrict__ xlo,
    int8_t* __restrict__ whi, int8_t* __restrict__ wlo,
    uint16_t* __restrict__ xT)
{
  if (blockIdx.x < 6144) {
    int i = blockIdx.x * 256 + threadIdx.x;  // 0..1572863
    const float* src; int8_t* dh; int8_t* dl; int idx; float s256, s;
    if (i < 1048576)      { src = x;  idx = i;           dh = xhi; dl = xlo;
                            s256 = INV_S256; s = INV_S; }
    else if (i < 1310720) { src = Wq; idx = i - 1048576; dh = whi; dl = wlo;
                            s256 = 512.0f; s = 131072.0f; }
    else                  { src = Wk; idx = i - 1310720; dh = whi + 1048576;
                            dl = wlo + 1048576; s256 = 512.0f; s = 131072.0f; }
    float4 v = ((const float4*)src)[idx];
    float vv[4] = {v.x, v.y, v.z, v.w};
    int hp = 0, lp = 0;
#pragma unroll
    for (int c = 0; c < 4; ++c) {
      int h = (int)lrintf(vv[c] * s256);
      h = h > 127 ? 127 : (h < -127 ? -127 : h);
      int l = (int)lrintf(vv[c] * s - 256.0f * (float)h);
      l = l > 127 ? 127 : (l < -127 ? -127 : l);
      hp |= (h & 0xff) << (8 * c);
      lp |= (l & 0xff) << (8 * c);
    }
    ((int*)dh)[idx] = hp;
    ((int*)dl)[idx] = lp;
  } else {
    __shared__ float tile[32][33];
    const int tb = blockIdx.x - 6144;   // 0..4095
    const int bx = tb & 31;             // D/32
    const int by = tb >> 5;             // N/32
    const int tx = threadIdx.x & 31;
    const int ty = threadIdx.x >> 5;    // 0..7
#pragma unroll
    for (int p = 0; p < 4; ++p) {
      const int row = by * 32 + ty + p * 8;
      tile[ty + p * 8][tx] = x[(size_t)row * 1024 + bx * 32 + tx];
    }
    __syncthreads();
#pragma unroll
    for (int p = 0; p < 4; ++p) {
      const int oc = ty + p * 8;
      __half hv = __float2half_rn(tile[tx][oc]);
      xT[(size_t)(bx * 32 + oc) * 4096 + by * 32 + tx] = *(uint16_t*)&hv;
    }
  }
}

extern "C" void kernel_launch(void* const* d_in, const int* in_sizes, int n_in,
                              void* d_out, int out_size, void* d_ws, size_t ws_size,
                              hipStream_t stream) {
  const int N = 4096, D = 1024;
  const float* x  = (const float*)d_in[0];
  const float* Wq = (const float*)d_in[1];
  const float* bq = (const float*)d_in[2];
  const float* Wk = (const float*)d_in[3];
  const float* bk = (const float*)d_in[4];
  float* out = (float*)d_out;

  // workspace layout (MiB offsets)
  char* w = (char*)d_ws;
  const size_t MiB = 1024 * 1024;
  int8_t*    xq_hi  = (int8_t*)   (w + 0  * MiB);  // [N x D]
  int8_t*    xq_lo  = (int8_t*)   (w + 4  * MiB);
  int8_t*    Wqk_hi = (int8_t*)   (w + 8  * MiB);  // [2048 x D]
  int8_t*    Wqk_lo = (int8_t*)   (w + 10 * MiB);
  int8_t*    qk_hi  = (int8_t*)   (w + 12 * MiB);  // [N x 2048]
  int8_t*    qk_lo  = (int8_t*)   (w + 20 * MiB);
  _Float16*  E      = (_Float16*) (w + 36 * MiB);  // [N x N] fp16, 32 MiB
  float2*    stats  = (float2*)   (w + 68 * MiB);  // [N x 32] (m,l), 1 MiB
  uint16_t*  xTh    = (uint16_t*) (w + 72 * MiB);  // [D x N] fp16
  // total 80 MiB

  // 1) fused quantization + transpose-cast  (6144 + 4096 blocks)
  quantT<<<10240, 256, 0, stream>>>(x, Wq, Wk, xq_hi, xq_lo, Wqk_hi, Wqk_lo,
                                    xTh);

  // 2) fused qk projection: i8 16x16x64, 3-MFMA, bias+quant epilogue
  gemm_proj_i8<<<dim3(2048 / 128, N / 128), 256, 0, stream>>>(
      xq_hi, xq_lo, Wqk_hi, Wqk_lo, bq, bk, qk_hi, qk_lo);

  // 3) S = q k^T + tile softmax stats -> E fp16, stats (m_t, l_t)
  gemm_s_stats<<<dim3(N / 128, N / 128), 256, 0, stream>>>(
      qk_hi, qk_lo, qk_hi + 1024, qk_lo + 1024, E, stats);

  // 4) out = sum_t beta_t (E_t x): 128x64 tiles, 2 K-groups in-block, direct store
  gemm_av<<<512, 256, 0, stream>>>((const uint16_t*)E, xTh, stats, out);

  (void)in_sizes; (void)n_in; (void)out_size; (void)ws_size;
}